// Round 2
// baseline (366.716 us; speedup 1.0000x reference)
//
#include <hip/hip_runtime.h>

typedef long long i64;

#define NB   131072
#define RPB  32          // rows per block
#define ND   128
#define NAUX 16

// ---- phase 3: one wave owns one expert; lane owns output cols (2*lane, 2*lane+1) ----
template<int K, int JBASE>
__device__ __forceinline__ void run_expert(
    const float* __restrict__ W, const int wexp, const int lane,
    const float (*feat)[80], const float (*disp)[4],
    const i64 row0, float* __restrict__ out)
{
    float2 wreg[K];
#pragma unroll
    for (int k = 0; k < K; ++k)
        wreg[k] = *(const float2*)(W + k * ND + 2 * lane);   // coalesced: 64 lanes x 8B

#pragma unroll 4
    for (int r = 0; r < RPB; ++r) {
        float a0 = 0.0f, a1 = 0.0f;
        const float* fp = &feat[r][JBASE];                   // wave-uniform LDS broadcast
#pragma unroll
        for (int k = 0; k < K; ++k) {
            float fv = fp[k];
            a0 = fmaf(fv, wreg[k].x, a0);
            a1 = fmaf(fv, wreg[k].y, a1);
        }
        const float sc = disp[r][wexp];
        float2 o = make_float2(a0 * sc, a1 * sc);
        *(float2*)(out + (row0 + r) * 512 + wexp * ND + 2 * lane) = o;
    }
}

__global__ __launch_bounds__(256) void mote_kernel(
    const float* __restrict__ timestamp,
    const float* __restrict__ aux,
    const float* __restrict__ router_W,   // [17,4]
    const float* __restrict__ router_b,   // [4]
    const float* __restrict__ freqs,      // [16]
    const float* __restrict__ fourier_W,  // [32,128]
    const float* __restrict__ knots,      // [16]
    const float* __restrict__ spline_W,   // [16,128]
    const float* __restrict__ centers,    // [16]
    const float* __restrict__ gauss_W,    // [16,128]
    const float* __restrict__ wav_centers,// [16]
    const float* __restrict__ wav_scales, // [16]
    const float* __restrict__ wavelet_W,  // [16,128]
    float* __restrict__ out)
{
    const int tid  = threadIdx.x;
    const int wv   = tid >> 6;
    const int lane = tid & 63;
    const i64 row0 = (i64)blockIdx.x * RPB;

    __shared__ float  sts[RPB];          // timestamps
    __shared__ float  feat[RPB][80];     // basis features per row
    __shared__ float  disp[RPB][4];      // top-2 gated weights
    __shared__ double dlog[RPB][4];      // f64 router logits
    __shared__ float  Cp[48], Sp[48];    // unified center/scale tables for j>=32

    // ---- phase 0: stage timestamps + param tables ----
    if (tid < RPB) {
        sts[tid] = timestamp[row0 + tid];
    } else if (tid >= 128 && tid < 176) {
        const int j = tid - 128;
        if (j < 16) {            // spline: exp(-((t-knot)*3.75)^2) = exp(-0.5*(dt*3.75*sqrt2)^2)
            Cp[j] = knots[j];
            Sp[j] = 5.30330085889911f;   // 3.75 * sqrt(2)
        } else if (j < 32) {     // gauss: exp(-dt^2) = exp(-0.5*(dt*sqrt2)^2)
            Cp[j] = centers[j - 16];
            Sp[j] = 1.41421356237310f;
        } else {                 // wavelet: u = dt / ws (true u needed for (1-u^2))
            Cp[j] = wav_centers[j - 32];
            Sp[j] = 1.0f / wav_scales[j - 32];
        }
    }
    __syncthreads();

    // ---- phase 1a: features (2560 values, 10 per thread) ----
    for (int v = tid; v < RPB * 80; v += 256) {
        const int r = v / 80;
        const int j = v - r * 80;
        const float t = sts[r];
        float val;
        if (j < 32) {
            const float fr = freqs[j < 16 ? j : j - 16];
            const float tf = t * fr;
            val = (j < 16) ? sinf(tf) : cosf(tf);
        } else {
            const int jj = j - 32;
            const float u = (t - Cp[jj]) * Sp[jj];
            const float e = expf(-0.5f * u * u);
            val = (j < 64) ? e : (1.0f - u * u) * e;
        }
        feat[r][j] = val;
    }

    // ---- phase 1b: router logits in f64 (ranking must match f64 numpy ref) ----
    if (tid < RPB * 4) {
        const int r = tid >> 2, e = tid & 3;
        const i64 row = row0 + r;
        double acc = (double)sts[r] * (double)router_W[e];
        const float* ar = aux + row * NAUX;
#pragma unroll
        for (int i = 0; i < NAUX; ++i)
            acc += (double)ar[i] * (double)router_W[(1 + i) * 4 + e];
        acc += (double)router_b[e];
        dlog[r][e] = acc;
    }
    __syncthreads();

    // ---- phase 2: softmax + stable top-2 (ties -> lower index, matches lax.top_k) ----
    if (tid < RPB * 4) {
        const int r = tid >> 2, e = tid & 3;
        const double l0 = dlog[r][0], l1 = dlog[r][1], l2 = dlog[r][2], l3 = dlog[r][3];
        const double le = dlog[r][e];
        const double m  = fmax(fmax(l0, l1), fmax(l2, l3));
        const double s  = exp(l0 - m) + exp(l1 - m) + exp(l2 - m) + exp(l3 - m);
        const float  we = (float)(exp(le - m) / s);

        int rank = 0;
        rank += (l0 > le) || (l0 == le && 0 < e);
        rank += (l1 > le) || (l1 == le && 1 < e);
        rank += (l2 > le) || (l2 == le && 2 < e);
        rank += (l3 > le) || (l3 == le && 3 < e);
        const bool top = (rank < 2);

        disp[r][e] = top ? we : 0.0f;
        const i64 row = row0 + r;
        out[(i64)NB * 512 + row * 4 + e]                 = we;                  // raw_weights
        out[(i64)NB * 512 + (i64)NB * 4 + row * 4 + e]   = top ? 1.0f : 0.0f;   // mask
    }
    __syncthreads();

    // ---- phase 3: expert dots, weights register-resident ----
    if (wv == 0)      run_expert<32,  0>(fourier_W, 0, lane, feat, disp, row0, out);
    else if (wv == 1) run_expert<16, 32>(spline_W,  1, lane, feat, disp, row0, out);
    else if (wv == 2) run_expert<16, 48>(gauss_W,   2, lane, feat, disp, row0, out);
    else              run_expert<16, 64>(wavelet_W, 3, lane, feat, disp, row0, out);
}

extern "C" void kernel_launch(void* const* d_in, const int* in_sizes, int n_in,
                              void* d_out, int out_size, void* d_ws, size_t ws_size,
                              hipStream_t stream) {
    const float* timestamp   = (const float*)d_in[0];
    const float* aux         = (const float*)d_in[1];
    const float* router_W    = (const float*)d_in[2];
    const float* router_b    = (const float*)d_in[3];
    const float* freqs       = (const float*)d_in[4];
    const float* fourier_W   = (const float*)d_in[5];
    const float* knots       = (const float*)d_in[6];
    const float* spline_W    = (const float*)d_in[7];
    const float* centers     = (const float*)d_in[8];
    const float* gauss_W     = (const float*)d_in[9];
    const float* wav_centers = (const float*)d_in[10];
    const float* wav_scales  = (const float*)d_in[11];
    const float* wavelet_W   = (const float*)d_in[12];
    float* out = (float*)d_out;

    mote_kernel<<<NB / RPB, 256, 0, stream>>>(
        timestamp, aux, router_W, router_b, freqs, fourier_W, knots, spline_W,
        centers, gauss_W, wav_centers, wav_scales, wavelet_W, out);
}

// Round 3
// 341.920 us; speedup vs baseline: 1.0725x; 1.0725x over previous
//
#include <hip/hip_runtime.h>

typedef long long i64;
typedef float f2v __attribute__((ext_vector_type(2)));

#define NB   131072
#define RPB  32          // rows per block
#define ND   128
#define NAUX 16

// ---- phase 3: wave owns expert wexp; lane owns output cols (2*lane, 2*lane+1) ----
template<int K, int JBASE>
__device__ __forceinline__ void run_expert(
    const float2* __restrict__ wreg, const int wexp, const int lane,
    const float (*feat)[80], const float (*disp)[4],
    const i64 row0, float* __restrict__ out)
{
#pragma unroll 2
    for (int r = 0; r < RPB; ++r) {
        // features: float4 LDS broadcast reads (ds_read_b128, conflict-free)
        float4 f[K / 4];
        const float4* fp = reinterpret_cast<const float4*>(&feat[r][JBASE]);
#pragma unroll
        for (int q = 0; q < K / 4; ++q) f[q] = fp[q];

        float a0 = 0.0f, a1 = 0.0f;
#pragma unroll
        for (int q = 0; q < K / 4; ++q) {
            a0 = fmaf(f[q].x, wreg[4 * q + 0].x, a0); a1 = fmaf(f[q].x, wreg[4 * q + 0].y, a1);
            a0 = fmaf(f[q].y, wreg[4 * q + 1].x, a0); a1 = fmaf(f[q].y, wreg[4 * q + 1].y, a1);
            a0 = fmaf(f[q].z, wreg[4 * q + 2].x, a0); a1 = fmaf(f[q].z, wreg[4 * q + 2].y, a1);
            a0 = fmaf(f[q].w, wreg[4 * q + 3].x, a0); a1 = fmaf(f[q].w, wreg[4 * q + 3].y, a1);
        }
        const float sc = disp[r][wexp];
        f2v o; o.x = a0 * sc; o.y = a1 * sc;
        __builtin_nontemporal_store(o, (f2v*)(out + (row0 + r) * 512 + wexp * ND + 2 * lane));
    }
}

__global__ __launch_bounds__(256) void mote_kernel(
    const float* __restrict__ timestamp,
    const float* __restrict__ aux,
    const float* __restrict__ router_W,   // [17,4]
    const float* __restrict__ router_b,   // [4]
    const float* __restrict__ freqs,      // [16]
    const float* __restrict__ fourier_W,  // [32,128]
    const float* __restrict__ knots,      // [16]
    const float* __restrict__ spline_W,   // [16,128]
    const float* __restrict__ centers,    // [16]
    const float* __restrict__ gauss_W,    // [16,128]
    const float* __restrict__ wav_centers,// [16]
    const float* __restrict__ wav_scales, // [16]
    const float* __restrict__ wavelet_W,  // [16,128]
    float* __restrict__ out)
{
    const int tid  = threadIdx.x;
    const int wv   = tid >> 6;
    const int lane = tid & 63;
    const i64 row0 = (i64)blockIdx.x * RPB;

    __shared__ __attribute__((aligned(16))) float feat[RPB][80];
    __shared__ float disp[RPB][4];

    // ---- preload expert weights into VGPRs (before the barrier; overlaps router work) ----
    const float* Wsel = (wv == 0) ? fourier_W : (wv == 1) ? spline_W
                      : (wv == 2) ? gauss_W   : wavelet_W;
    float2 wreg[32];
#pragma unroll
    for (int k = 0; k < 16; ++k)
        wreg[k] = *(const float2*)(Wsel + k * ND + 2 * lane);
    if (wv == 0) {   // wave-uniform branch
#pragma unroll
        for (int k = 16; k < 32; ++k)
            wreg[k] = *(const float2*)(Wsel + k * ND + 2 * lane);
    }

    // ---- phase 1: basis features -> LDS (2560 values, 10/thread) ----
#pragma unroll
    for (int it = 0; it < (RPB * 80) / 256; ++it) {
        const int v = tid + it * 256;
        const int r = v / 80;
        const int j = v - r * 80;
        const float t = timestamp[row0 + r];
        float val;
        if (j < 32) {
            const float tf = t * freqs[j & 15];
            val = (j < 16) ? __sinf(tf) : __cosf(tf);
        } else if (j < 48) {
            const float d = (t - knots[j - 32]) * 3.75f;   // 1/h, h = 4/15
            val = __expf(-d * d);
        } else if (j < 64) {
            const float d = t - centers[j - 48];
            val = __expf(-d * d);
        } else {
            const float u = (t - wav_centers[j - 64]) / wav_scales[j - 64];
            val = (1.0f - u * u) * __expf(-0.5f * u * u);
        }
        feat[r][j] = val;
    }

    // ---- phase 2: router logits (f64 rank, f32 softmax), top-2, gate weights ----
    if (tid < RPB * 4) {
        const int r = tid >> 2, e = tid & 3;
        const i64 row = row0 + r;

        double acc = (double)timestamp[row] * (double)router_W[e];
        const float4* a4 = (const float4*)(aux + row * NAUX);
#pragma unroll
        for (int q = 0; q < 4; ++q) {
            const float4 a = a4[q];
            acc = fma((double)a.x, (double)router_W[(1 + 4 * q + 0) * 4 + e], acc);
            acc = fma((double)a.y, (double)router_W[(1 + 4 * q + 1) * 4 + e], acc);
            acc = fma((double)a.z, (double)router_W[(1 + 4 * q + 2) * 4 + e], acc);
            acc = fma((double)a.w, (double)router_W[(1 + 4 * q + 3) * 4 + e], acc);
        }
        acc += (double)router_b[e];

        // gather the row's 4 logits via shuffle (lanes 4r..4r+3 of this wave)
        const int lb = (tid & 63) & ~3;
        const double l0 = __shfl(acc, lb + 0, 64);
        const double l1 = __shfl(acc, lb + 1, 64);
        const double l2 = __shfl(acc, lb + 2, 64);
        const double l3 = __shfl(acc, lb + 3, 64);

        // rank of expert e, descending, stable by index (matches lax.top_k on f64)
        int rank = 0;
        rank += (l0 > acc) || (l0 == acc && 0 < e);
        rank += (l1 > acc) || (l1 == acc && 1 < e);
        rank += (l2 > acc) || (l2 == acc && 2 < e);
        rank += (l3 > acc) || (l3 == acc && 3 < e);
        const bool top = (rank < 2);

        // f32 softmax (weights only need ~1e-2 accuracy; ranking already settled in f64)
        const double m = fmax(fmax(l0, l1), fmax(l2, l3));
        const float x0 = __expf((float)(l0 - m));
        const float x1 = __expf((float)(l1 - m));
        const float x2 = __expf((float)(l2 - m));
        const float x3 = __expf((float)(l3 - m));
        const float we = __expf((float)(acc - m)) / (x0 + x1 + x2 + x3);

        disp[r][e] = top ? we : 0.0f;
        out[(i64)NB * 512 + row * 4 + e]               = we;                  // raw_weights
        out[(i64)NB * 516 + row * 4 + e]               = top ? 1.0f : 0.0f;   // mask
    }
    __syncthreads();

    // ---- phase 3: expert dots, weights register-resident ----
    if (wv == 0)      run_expert<32,  0>(wreg, 0, lane, feat, disp, row0, out);
    else if (wv == 1) run_expert<16, 32>(wreg, 1, lane, feat, disp, row0, out);
    else if (wv == 2) run_expert<16, 48>(wreg, 2, lane, feat, disp, row0, out);
    else              run_expert<16, 64>(wreg, 3, lane, feat, disp, row0, out);
}

extern "C" void kernel_launch(void* const* d_in, const int* in_sizes, int n_in,
                              void* d_out, int out_size, void* d_ws, size_t ws_size,
                              hipStream_t stream) {
    const float* timestamp   = (const float*)d_in[0];
    const float* aux         = (const float*)d_in[1];
    const float* router_W    = (const float*)d_in[2];
    const float* router_b    = (const float*)d_in[3];
    const float* freqs       = (const float*)d_in[4];
    const float* fourier_W   = (const float*)d_in[5];
    const float* knots       = (const float*)d_in[6];
    const float* spline_W    = (const float*)d_in[7];
    const float* centers     = (const float*)d_in[8];
    const float* gauss_W     = (const float*)d_in[9];
    const float* wav_centers = (const float*)d_in[10];
    const float* wav_scales  = (const float*)d_in[11];
    const float* wavelet_W   = (const float*)d_in[12];
    float* out = (float*)d_out;

    mote_kernel<<<NB / RPB, 256, 0, stream>>>(
        timestamp, aux, router_W, router_b, freqs, fourier_W, knots, spline_W,
        centers, gauss_W, wav_centers, wav_scales, wavelet_W, out);
}